// Round 12
// baseline (135.129 us; speedup 1.0000x reference)
//
#include <hip/hip_runtime.h>
#include <hip/hip_bf16.h>
#include <math.h>

// Problem constants: B=8, H=W=32, D=512, NH=8, DKH=DVH=64
#define TOK 8192
#define DMODEL 512
#define SEQ 1024
#define NHEADS 8
#define DH 64
#define NBATCH 8

typedef __attribute__((ext_vector_type(8))) short short8v;   // 8 bf16 = 4 VGPR
typedef __attribute__((ext_vector_type(4))) float f32x4;
typedef __attribute__((ext_vector_type(4))) int i32x4;

#define MFMA16(a, b, c) __builtin_amdgcn_mfma_f32_16x16x32_bf16(a, b, c, 0, 0, 0)

// HW RNE f32->bf16 (single v_cvt; pairs fuse to v_cvt_pk_bf16_f32)
__device__ __forceinline__ unsigned short f2bf(float x) {
  __hip_bfloat16 h = __float2bfloat16(x);
  unsigned short u;
  __builtin_memcpy(&u, &h, 2);
  return u;
}
__device__ __forceinline__ unsigned int pk2(float a, float b) {
  return (unsigned int)f2bf(a) | ((unsigned int)f2bf(b) << 16);
}

// ---------------------------------------------------------------------------
// Weight transpose + convert: Wt[n][k] = bf16(W[k][n]), 512x512. 4 matrices
// in one dispatch (blockIdx.z selects).
// ---------------------------------------------------------------------------
__global__ __launch_bounds__(256) void wtr4_kernel(
    const float* __restrict__ W0, const float* __restrict__ W1,
    const float* __restrict__ W2, const float* __restrict__ W3,
    unsigned short* __restrict__ T0, unsigned short* __restrict__ T1,
    unsigned short* __restrict__ T2, unsigned short* __restrict__ T3) {
  __shared__ unsigned short tile[64][72];
  const int z = blockIdx.z;
  const float* W = (z == 0) ? W0 : (z == 1) ? W1 : (z == 2) ? W2 : W3;
  unsigned short* Wt = (z == 0) ? T0 : (z == 1) ? T1 : (z == 2) ? T2 : T3;
  const int kt = blockIdx.x, nt = blockIdx.y;
  const int t = threadIdx.x, r = t >> 2, c0 = (t & 3) * 16;
  const float* src = W + (size_t)(kt * 64 + r) * 512 + nt * 64 + c0;
  short8v v0, v1;
#pragma unroll
  for (int e = 0; e < 4; ++e) {
    float4 f = *reinterpret_cast<const float4*>(src + e * 4);
    short* dstv = (e < 2) ? (short*)&v0 : (short*)&v1;
    dstv[(e & 1) * 4 + 0] = (short)f2bf(f.x);
    dstv[(e & 1) * 4 + 1] = (short)f2bf(f.y);
    dstv[(e & 1) * 4 + 2] = (short)f2bf(f.z);
    dstv[(e & 1) * 4 + 3] = (short)f2bf(f.w);
  }
  *reinterpret_cast<short8v*>(&tile[r][c0]) = v0;
  *reinterpret_cast<short8v*>(&tile[r][c0 + 8]) = v1;
  __syncthreads();
  short8v o0, o1;
#pragma unroll
  for (int e = 0; e < 8; ++e) o0[e] = (short)tile[c0 + e][r];
#pragma unroll
  for (int e = 0; e < 8; ++e) o1[e] = (short)tile[c0 + 8 + e][r];
  unsigned short* dst = Wt + (size_t)(nt * 64 + r) * 512 + kt * 64 + c0;
  *reinterpret_cast<short8v*>(dst) = o0;
  *reinterpret_cast<short8v*>(dst + 8) = o1;
}

// ---------------------------------------------------------------------------
// MFMA GEMM body: C[M,512] = (A[M,512] @ Wt^T + bias) * scale
// 128x128 tile, 256 thr (4 waves 2x2, 64x64 each), BK=64, padded LDS.
// ---------------------------------------------------------------------------
template <int AF32, int OUTMODE>
__device__ __forceinline__ void gemm_body(
    const void* __restrict__ Ap, const unsigned short* __restrict__ Wt,
    const float* __restrict__ bias, float scale, void* __restrict__ Cout) {
  __shared__ unsigned short Asl[128][72];
  __shared__ unsigned short Bsl[128][72];
  const int t = threadIdx.x;
  const int w = t >> 6, lane = t & 63, li = lane & 15, lg = lane >> 4;
  const int wr = w >> 1, wc = w & 1;
  const int rowBase = blockIdx.y * 128, colBase = blockIdx.x * 128;

  f32x4 zero4 = {0.f, 0.f, 0.f, 0.f};
  f32x4 acc[4][4];
#pragma unroll
  for (int mi = 0; mi < 4; ++mi)
#pragma unroll
    for (int nj = 0; nj < 4; ++nj) acc[mi][nj] = zero4;

  const int sr = t >> 1, sh = (t & 1) * 32;  // staging: row, 32-elem half

  for (int k0 = 0; k0 < 512; k0 += 64) {
    if (AF32) {
      const float* src = reinterpret_cast<const float*>(Ap) +
                         (size_t)(rowBase + sr) * 512 + k0 + sh;
#pragma unroll
      for (int qq = 0; qq < 4; ++qq) {
        float4 f0 = *reinterpret_cast<const float4*>(src + qq * 8);
        float4 f1 = *reinterpret_cast<const float4*>(src + qq * 8 + 4);
        short8v o;
        o[0] = (short)f2bf(f0.x); o[1] = (short)f2bf(f0.y);
        o[2] = (short)f2bf(f0.z); o[3] = (short)f2bf(f0.w);
        o[4] = (short)f2bf(f1.x); o[5] = (short)f2bf(f1.y);
        o[6] = (short)f2bf(f1.z); o[7] = (short)f2bf(f1.w);
        *reinterpret_cast<short8v*>(&Asl[sr][sh + qq * 8]) = o;
      }
    } else {
      const unsigned short* src = reinterpret_cast<const unsigned short*>(Ap) +
                                  (size_t)(rowBase + sr) * 512 + k0 + sh;
#pragma unroll
      for (int qq = 0; qq < 4; ++qq)
        *reinterpret_cast<short8v*>(&Asl[sr][sh + qq * 8]) =
            *reinterpret_cast<const short8v*>(src + qq * 8);
    }
    {
      const unsigned short* src = Wt + (size_t)(colBase + sr) * 512 + k0 + sh;
#pragma unroll
      for (int qq = 0; qq < 4; ++qq)
        *reinterpret_cast<short8v*>(&Bsl[sr][sh + qq * 8]) =
            *reinterpret_cast<const short8v*>(src + qq * 8);
    }
    __syncthreads();
#pragma unroll
    for (int kk = 0; kk < 2; ++kk) {
      short8v af[4], bf[4];
#pragma unroll
      for (int mi = 0; mi < 4; ++mi)
        af[mi] = *reinterpret_cast<short8v*>(&Asl[wr * 64 + mi * 16 + li][kk * 32 + lg * 8]);
#pragma unroll
      for (int nj = 0; nj < 4; ++nj)
        bf[nj] = *reinterpret_cast<short8v*>(&Bsl[wc * 64 + nj * 16 + li][kk * 32 + lg * 8]);
#pragma unroll
      for (int mi = 0; mi < 4; ++mi)
#pragma unroll
        for (int nj = 0; nj < 4; ++nj) acc[mi][nj] = MFMA16(af[mi], bf[nj], acc[mi][nj]);
    }
    __syncthreads();
  }

#pragma unroll
  for (int nj = 0; nj < 4; ++nj) {
    const int col = colBase + wc * 64 + nj * 16 + li;
    const float bv = bias[col];
#pragma unroll
    for (int mi = 0; mi < 4; ++mi) {
      const int row0 = rowBase + wr * 64 + mi * 16 + lg * 4;
      if (OUTMODE == 2) {
        const int hh = col >> 6, dd = col & 63;
        const int bb = row0 >> 10, jj = row0 & 1023;
        unsigned short* dst =
            reinterpret_cast<unsigned short*>(Cout) +
            ((size_t)((bb * 8 + hh) * 64 + dd)) * SEQ + jj;
        float v0 = (acc[mi][nj][0] + bv) * scale;
        float v1 = (acc[mi][nj][1] + bv) * scale;
        float v2 = (acc[mi][nj][2] + bv) * scale;
        float v3 = (acc[mi][nj][3] + bv) * scale;
        *reinterpret_cast<uint2*>(dst) = make_uint2(pk2(v0, v1), pk2(v2, v3));
      } else {
#pragma unroll
        for (int rr = 0; rr < 4; ++rr) {
          const int row = row0 + rr;
          const float v = (acc[mi][nj][rr] + bv) * scale;
          if (OUTMODE == 1)
            reinterpret_cast<float*>(Cout)[(size_t)row * 512 + col] = v;
          else
            reinterpret_cast<unsigned short*>(Cout)[(size_t)row * 512 + col] = f2bf(v);
        }
      }
    }
  }
}

__global__ __launch_bounds__(256) void gemm_qk(
    const float* __restrict__ q, const float* __restrict__ k,
    const unsigned short* __restrict__ Wqt, const unsigned short* __restrict__ Wkt,
    const float* __restrict__ bq, const float* __restrict__ bk,
    unsigned short* __restrict__ qpb, unsigned short* __restrict__ kpb) {
  const int z = blockIdx.z;
  const void* A = z ? (const void*)k : (const void*)q;
  const unsigned short* Wt = z ? Wkt : Wqt;
  const float* bias = z ? bk : bq;
  const float scale = z ? 1.0f : 0.125f;
  void* C = z ? (void*)kpb : (void*)qpb;
  gemm_body<1, 0>(A, Wt, bias, scale, C);
}

__global__ __launch_bounds__(256) void gemm_vp(
    const unsigned short* __restrict__ kpb, const unsigned short* __restrict__ Wvt,
    const float* __restrict__ bv, unsigned short* __restrict__ vtb) {
  gemm_body<0, 2>(kpb, Wvt, bv, 1.0f, vtb);
}

__global__ __launch_bounds__(256) void gemm_out(
    const unsigned short* __restrict__ attnb, const unsigned short* __restrict__ Wot,
    const float* __restrict__ bo, float* __restrict__ out) {
  gemm_body<0, 1>(attnb, Wot, bo, 1.0f, out);
}

// ---------------------------------------------------------------------------
// MFMA flash attention, 32 queries/wave (two 16-q groups share each K/V
// fragment read -> per-CU LDS fragment traffic halves; independent g-chains
// give 2x in-wave ILP). Block = 2 waves (128 thr, 64 q), grid 1024
// (4 blocks/CU). LDS 27.6 KB: single-buffered K/V + per-(wave,g) P.
// ---------------------------------------------------------------------------
__global__ __launch_bounds__(128, 2) void attn_mfma(
    const unsigned short* __restrict__ qp, const unsigned short* __restrict__ kp,
    const unsigned short* __restrict__ vt, const float* __restrict__ pos,
    const int* __restrict__ qmask, const int* __restrict__ kmask,
    unsigned short* __restrict__ outb) {
  const int bx = blockIdx.x;
  const int qc = bx >> 6, h = (bx >> 3) & 7, b = bx & 7;  // qc 0..15
  const int t = threadIdx.x, w = t >> 6, lane = t & 63, li = lane & 15, lg = lane >> 4;
  const int qrow = qc * 64 + w * 32;  // wave's 32-query base

  __shared__ unsigned short Kl[64 * 72];     // [key][dim]
  __shared__ unsigned short Vl[64 * 72];     // [dim][key] (V^T)
  __shared__ unsigned short Pl[4][16 * 72];  // [w*2+g][query][key]

  // Q fragments + masks per group
  short8v qf[2][2];
  int qmv[2];
#pragma unroll
  for (int g = 0; g < 2; ++g) {
    const size_t qg = (size_t)(b * SEQ + qrow + g * 16 + li) * DMODEL + h * DH;
    qf[g][0] = *reinterpret_cast<const short8v*>(qp + qg + lg * 8);
    qf[g][1] = *reinterpret_cast<const short8v*>(qp + qg + 32 + lg * 8);
    qmv[g] = qmask[b * SEQ + qrow + g * 16 + li];
  }

  f32x4 zero4 = {0.f, 0.f, 0.f, 0.f};
  f32x4 acc_o[2][4];
#pragma unroll
  for (int g = 0; g < 2; ++g)
#pragma unroll
    for (int n = 0; n < 4; ++n) acc_o[g][n] = zero4;
  float m[2] = {-3e38f, -3e38f}, l[2] = {0.f, 0.f};

  // staging: 128 threads; thread t covers row t>>1, 32-short half (t&1)*32
  const int srow = t >> 1, schk = (t & 1) * 32;
  const unsigned short* kgp = kp + (size_t)(b * SEQ + srow) * DMODEL + h * DH + schk;
  const unsigned short* vgp = vt + ((size_t)((b * 8 + h) * 64) + srow) * SEQ + schk;
  const int sldst = srow * 72 + schk;

  const float* posb0 = pos + (size_t)(b * SEQ + qrow + li) * SEQ;
  const float* posb1 = posb0 + (size_t)16 * SEQ;
  const int* kmb = kmask + b * SEQ;

  // prologue: stage tile 0
  {
#pragma unroll
    for (int qq = 0; qq < 4; ++qq) {
      *reinterpret_cast<short8v*>(&Kl[sldst + qq * 8]) =
          *reinterpret_cast<const short8v*>(kgp + qq * 8);
      *reinterpret_cast<short8v*>(&Vl[sldst + qq * 8]) =
          *reinterpret_cast<const short8v*>(vgp + qq * 8);
    }
  }
  __syncthreads();

  for (int kt = 0; kt < 16; ++kt) {
    const int kbase = kt * 64;

    // issue next-tile staging loads early (written to LDS at iter end)
    short8v kr[4], vr[4];
    if (kt < 15) {
#pragma unroll
      for (int qq = 0; qq < 4; ++qq) {
        kr[qq] = *reinterpret_cast<const short8v*>(kgp + (size_t)(kbase + 64) * DMODEL + qq * 8);
        vr[qq] = *reinterpret_cast<const short8v*>(vgp + kbase + 64 + qq * 8);
      }
    }

    // pos / kmask for current tile (dense vectors; keys kbase+n*16+lg*4+r)
    f32x4 pvn[2][4];
    i32x4 kmn[4];
#pragma unroll
    for (int n = 0; n < 4; ++n) {
      pvn[0][n] = *reinterpret_cast<const f32x4*>(posb0 + kbase + n * 16 + lg * 4);
      pvn[1][n] = *reinterpret_cast<const f32x4*>(posb1 + kbase + n * 16 + lg * 4);
      kmn[n] = *reinterpret_cast<const i32x4*>(kmb + kbase + n * 16 + lg * 4);
    }

    // ---- swapped QK^T, both groups share each K fragment read
    f32x4 x4[2][4];
    __builtin_amdgcn_s_setprio(1);
#pragma unroll
    for (int n = 0; n < 4; ++n) {
      short8v kfa = *reinterpret_cast<short8v*>(&Kl[(n * 16 + li) * 72 + lg * 8]);
      short8v kfb = *reinterpret_cast<short8v*>(&Kl[(n * 16 + li) * 72 + 32 + lg * 8]);
      x4[0][n] = MFMA16(kfa, qf[0][0], zero4);
      x4[1][n] = MFMA16(kfa, qf[1][0], zero4);
      x4[0][n] = MFMA16(kfb, qf[0][1], x4[0][n]);
      x4[1][n] = MFMA16(kfb, qf[1][1], x4[1][n]);
    }
    __builtin_amdgcn_s_setprio(0);

    // ---- scores + mask + online softmax per group (query per li lane)
#pragma unroll
    for (int g = 0; g < 2; ++g) {
      float x[4][4];
      float tm = -3e38f;
#pragma unroll
      for (int n = 0; n < 4; ++n)
#pragma unroll
        for (int r = 0; r < 4; ++r) {
          float xx = x4[g][n][r] + pvn[g][n][r];
          if ((qmv[g] != 0) != (kmn[n][r] != 0)) xx = -1e30f;
          x[n][r] = xx;
          tm = fmaxf(tm, xx);
        }
      tm = fmaxf(tm, __shfl_xor(tm, 16));
      tm = fmaxf(tm, __shfl_xor(tm, 32));
      const float mn = fmaxf(m[g], tm);
      const float rs = __expf(m[g] - mn);
      m[g] = mn;
      float psum = 0.f;
#pragma unroll
      for (int n = 0; n < 4; ++n)
#pragma unroll
        for (int r = 0; r < 4; ++r) {
          const float p = __expf(x[n][r] - m[g]);
          x[n][r] = p;
          psum += p;
        }
      psum += __shfl_xor(psum, 16);
      psum += __shfl_xor(psum, 32);
      l[g] = l[g] * rs + psum;
      float rsb[4];
#pragma unroll
      for (int r = 0; r < 4; ++r) rsb[r] = __shfl(rs, lg * 4 + r, 16);
#pragma unroll
      for (int n = 0; n < 4; ++n)
#pragma unroll
        for (int r = 0; r < 4; ++r) acc_o[g][n][r] *= rsb[r];

      // P^T -> per-(wave,g) LDS region
#pragma unroll
      for (int n = 0; n < 4; ++n) {
        *reinterpret_cast<uint2*>(&Pl[w * 2 + g][li * 72 + n * 16 + lg * 4]) =
            make_uint2(pk2(x[n][0], x[n][1]), pk2(x[n][2], x[n][3]));
      }
    }
    asm volatile("s_waitcnt lgkmcnt(0)" ::: "memory");
    __builtin_amdgcn_sched_barrier(0);

    short8v pf[2][2];
#pragma unroll
    for (int g = 0; g < 2; ++g) {
      pf[g][0] = *reinterpret_cast<short8v*>(&Pl[w * 2 + g][li * 72 + lg * 8]);
      pf[g][1] = *reinterpret_cast<short8v*>(&Pl[w * 2 + g][li * 72 + 32 + lg * 8]);
    }

    // ---- PV, both groups share each V fragment read
    __builtin_amdgcn_s_setprio(1);
#pragma unroll
    for (int n = 0; n < 4; ++n) {
      short8v vfa = *reinterpret_cast<short8v*>(&Vl[(n * 16 + li) * 72 + lg * 8]);
      short8v vfb = *reinterpret_cast<short8v*>(&Vl[(n * 16 + li) * 72 + 32 + lg * 8]);
      acc_o[0][n] = MFMA16(pf[0][0], vfa, acc_o[0][n]);
      acc_o[1][n] = MFMA16(pf[1][0], vfa, acc_o[1][n]);
      acc_o[0][n] = MFMA16(pf[0][1], vfb, acc_o[0][n]);
      acc_o[1][n] = MFMA16(pf[1][1], vfb, acc_o[1][n]);
    }
    __builtin_amdgcn_s_setprio(0);

    // ---- single-buffer swap: drain readers, overwrite, publish
    if (kt < 15) {
      __syncthreads();
#pragma unroll
      for (int qq = 0; qq < 4; ++qq) {
        *reinterpret_cast<short8v*>(&Kl[sldst + qq * 8]) = kr[qq];
        *reinterpret_cast<short8v*>(&Vl[sldst + qq * 8]) = vr[qq];
      }
      __syncthreads();
    }
  }

  // ---- epilogue per group
#pragma unroll
  for (int g = 0; g < 2; ++g) {
    const float linv = 1.f / l[g];
    float lb[4];
#pragma unroll
    for (int r = 0; r < 4; ++r) lb[r] = __shfl(linv, lg * 4 + r, 16);
    unsigned short* ob = outb + (size_t)(b * SEQ + qrow + g * 16) * DMODEL + h * DH;
#pragma unroll
    for (int n = 0; n < 4; ++n)
#pragma unroll
      for (int r = 0; r < 4; ++r)
        ob[(size_t)(lg * 4 + r) * DMODEL + n * 16 + li] = f2bf(acc_o[g][n][r] * lb[r]);
  }
}

// ---------------------------------------------------------------------------
extern "C" void kernel_launch(void* const* d_in, const int* in_sizes, int n_in,
                              void* d_out, int out_size, void* d_ws, size_t ws_size,
                              hipStream_t stream) {
  const float* q   = (const float*)d_in[0];
  const float* k   = (const float*)d_in[1];
  const int*   qm  = (const int*)d_in[2];
  const int*   km  = (const int*)d_in[3];
  const float* pos = (const float*)d_in[4];
  const float* Wq  = (const float*)d_in[5];
  const float* bq  = (const float*)d_in[6];
  const float* Wk  = (const float*)d_in[7];
  const float* bk  = (const float*)d_in[8];
  const float* Wv  = (const float*)d_in[9];
  const float* bv  = (const float*)d_in[10];
  const float* Wo  = (const float*)d_in[11];
  const float* bo  = (const float*)d_in[12];
  float* out = (float*)d_out;

  char* ws = (char*)d_ws;
  const size_t MB8 = (size_t)TOK * DMODEL * 2;  // 8 MB per bf16 [8192][512]
  unsigned short* qpb   = (unsigned short*)(ws);
  unsigned short* kpb   = (unsigned short*)(ws + 1 * MB8);
  unsigned short* attnb = (unsigned short*)(ws + 2 * MB8);
  unsigned short* vtb   = (unsigned short*)(ws + 3 * MB8);
  unsigned short* Wqt   = (unsigned short*)(ws + 4 * MB8);
  unsigned short* Wkt   = Wqt + (size_t)512 * 512;
  unsigned short* Wvt   = Wkt + (size_t)512 * 512;
  unsigned short* Wot   = Wvt + (size_t)512 * 512;

  hipLaunchKernelGGL(wtr4_kernel, dim3(8, 8, 4), dim3(256), 0, stream,
                     Wq, Wk, Wv, Wo, Wqt, Wkt, Wvt, Wot);

  const dim3 ggrid(DMODEL / 128, TOK / 128);  // (4, 64)
  hipLaunchKernelGGL(gemm_qk, dim3(4, 64, 2), dim3(256), 0, stream,
                     q, k, Wqt, Wkt, bq, bk, qpb, kpb);
  hipLaunchKernelGGL(gemm_vp, ggrid, dim3(256), 0, stream, kpb, Wvt, bv, vtb);

  // grid 1024: bx = qc*64 + h*8 + b  (qc 0..15)
  hipLaunchKernelGGL(attn_mfma, dim3(1024), dim3(128), 0, stream,
                     qpb, kpb, vtb, pos, qm, km, attnb);

  hipLaunchKernelGGL(gemm_out, ggrid, dim3(256), 0, stream, attnb, Wot, bo, out);
}

// Round 13
// 110.569 us; speedup vs baseline: 1.2221x; 1.2221x over previous
//
#include <hip/hip_runtime.h>
#include <hip/hip_bf16.h>
#include <math.h>

// Problem constants: B=8, H=W=32, D=512, NH=8, DKH=DVH=64
#define TOK 8192
#define DMODEL 512
#define SEQ 1024
#define NHEADS 8
#define DH 64
#define NBATCH 8

typedef __attribute__((ext_vector_type(8))) short short8v;   // 8 bf16 = 4 VGPR
typedef __attribute__((ext_vector_type(4))) float f32x4;
typedef __attribute__((ext_vector_type(4))) int i32x4;

#define MFMA16(a, b, c) __builtin_amdgcn_mfma_f32_16x16x32_bf16(a, b, c, 0, 0, 0)

// HW RNE f32->bf16 (single v_cvt; pairs fuse to v_cvt_pk_bf16_f32)
__device__ __forceinline__ unsigned short f2bf(float x) {
  __hip_bfloat16 h = __float2bfloat16(x);
  unsigned short u;
  __builtin_memcpy(&u, &h, 2);
  return u;
}
__device__ __forceinline__ unsigned int pk2(float a, float b) {
  return (unsigned int)f2bf(a) | ((unsigned int)f2bf(b) << 16);
}

// ---------------------------------------------------------------------------
// Weight transpose + convert: Wt[n][k] = bf16(W[k][n]), 512x512. 4 matrices
// in one dispatch (blockIdx.z selects).
// ---------------------------------------------------------------------------
__global__ __launch_bounds__(256) void wtr4_kernel(
    const float* __restrict__ W0, const float* __restrict__ W1,
    const float* __restrict__ W2, const float* __restrict__ W3,
    unsigned short* __restrict__ T0, unsigned short* __restrict__ T1,
    unsigned short* __restrict__ T2, unsigned short* __restrict__ T3) {
  __shared__ unsigned short tile[64][72];
  const int z = blockIdx.z;
  const float* W = (z == 0) ? W0 : (z == 1) ? W1 : (z == 2) ? W2 : W3;
  unsigned short* Wt = (z == 0) ? T0 : (z == 1) ? T1 : (z == 2) ? T2 : T3;
  const int kt = blockIdx.x, nt = blockIdx.y;
  const int t = threadIdx.x, r = t >> 2, c0 = (t & 3) * 16;
  const float* src = W + (size_t)(kt * 64 + r) * 512 + nt * 64 + c0;
  short8v v0, v1;
#pragma unroll
  for (int e = 0; e < 4; ++e) {
    float4 f = *reinterpret_cast<const float4*>(src + e * 4);
    short* dstv = (e < 2) ? (short*)&v0 : (short*)&v1;
    dstv[(e & 1) * 4 + 0] = (short)f2bf(f.x);
    dstv[(e & 1) * 4 + 1] = (short)f2bf(f.y);
    dstv[(e & 1) * 4 + 2] = (short)f2bf(f.z);
    dstv[(e & 1) * 4 + 3] = (short)f2bf(f.w);
  }
  *reinterpret_cast<short8v*>(&tile[r][c0]) = v0;
  *reinterpret_cast<short8v*>(&tile[r][c0 + 8]) = v1;
  __syncthreads();
  short8v o0, o1;
#pragma unroll
  for (int e = 0; e < 8; ++e) o0[e] = (short)tile[c0 + e][r];
#pragma unroll
  for (int e = 0; e < 8; ++e) o1[e] = (short)tile[c0 + 8 + e][r];
  unsigned short* dst = Wt + (size_t)(nt * 64 + r) * 512 + kt * 64 + c0;
  *reinterpret_cast<short8v*>(dst) = o0;
  *reinterpret_cast<short8v*>(dst + 8) = o1;
}

// ---------------------------------------------------------------------------
// MFMA GEMM body with T14 register prefetch: per K-step, issue next tile's
// global loads into regs FIRST, run MFMA on the staged LDS tile (hides the
// ~300-500cy global latency inside one block -- critical at 1 block/CU),
// then barrier + ds_write + barrier. 128x128 tile, 256 thr (4 waves 2x2).
// AF32: A is f32 (convert during staging). OUTMODE: 0=bf16 row-major,
// 1=f32 row-major, 2=bf16 transposed into vt[(b*8+h)*64+d][token].
// ---------------------------------------------------------------------------
template <int AF32, int OUTMODE>
__device__ __forceinline__ void gemm_body(
    const void* __restrict__ Ap, const unsigned short* __restrict__ Wt,
    const float* __restrict__ bias, float scale, void* __restrict__ Cout) {
  __shared__ unsigned short Asl[128][72];
  __shared__ unsigned short Bsl[128][72];
  const int t = threadIdx.x;
  const int w = t >> 6, lane = t & 63, li = lane & 15, lg = lane >> 4;
  const int wr = w >> 1, wc = w & 1;
  const int rowBase = blockIdx.y * 128, colBase = blockIdx.x * 128;

  f32x4 zero4 = {0.f, 0.f, 0.f, 0.f};
  f32x4 acc[4][4];
#pragma unroll
  for (int mi = 0; mi < 4; ++mi)
#pragma unroll
    for (int nj = 0; nj < 4; ++nj) acc[mi][nj] = zero4;

  const int sr = t >> 1, sh = (t & 1) * 32;  // staging: row, 32-elem half
  const float* af32base =
      AF32 ? reinterpret_cast<const float*>(Ap) + (size_t)(rowBase + sr) * 512 + sh : nullptr;
  const unsigned short* abf16base =
      AF32 ? nullptr
           : reinterpret_cast<const unsigned short*>(Ap) + (size_t)(rowBase + sr) * 512 + sh;
  const unsigned short* bbase = Wt + (size_t)(colBase + sr) * 512 + sh;

  // ---- stage tile 0 (no overlap available for the first tile)
  {
    if (AF32) {
#pragma unroll
      for (int qq = 0; qq < 4; ++qq) {
        float4 f0 = *reinterpret_cast<const float4*>(af32base + qq * 8);
        float4 f1 = *reinterpret_cast<const float4*>(af32base + qq * 8 + 4);
        short8v o;
        o[0] = (short)f2bf(f0.x); o[1] = (short)f2bf(f0.y);
        o[2] = (short)f2bf(f0.z); o[3] = (short)f2bf(f0.w);
        o[4] = (short)f2bf(f1.x); o[5] = (short)f2bf(f1.y);
        o[6] = (short)f2bf(f1.z); o[7] = (short)f2bf(f1.w);
        *reinterpret_cast<short8v*>(&Asl[sr][sh + qq * 8]) = o;
      }
    } else {
#pragma unroll
      for (int qq = 0; qq < 4; ++qq)
        *reinterpret_cast<short8v*>(&Asl[sr][sh + qq * 8]) =
            *reinterpret_cast<const short8v*>(abf16base + qq * 8);
    }
#pragma unroll
    for (int qq = 0; qq < 4; ++qq)
      *reinterpret_cast<short8v*>(&Bsl[sr][sh + qq * 8]) =
          *reinterpret_cast<const short8v*>(bbase + qq * 8);
  }
  __syncthreads();

  for (int kt = 0; kt < 8; ++kt) {
    const int knext = (kt + 1) * 64;

    // ---- issue next tile's global loads into registers (T14)
    float4 paf[8];       // AF32 prefetch
    short8v pab[4];      // bf16 A prefetch
    short8v pbb[4];      // B prefetch
    if (kt < 7) {
      if (AF32) {
#pragma unroll
        for (int qq = 0; qq < 4; ++qq) {
          paf[2 * qq]     = *reinterpret_cast<const float4*>(af32base + knext + qq * 8);
          paf[2 * qq + 1] = *reinterpret_cast<const float4*>(af32base + knext + qq * 8 + 4);
        }
      } else {
#pragma unroll
        for (int qq = 0; qq < 4; ++qq)
          pab[qq] = *reinterpret_cast<const short8v*>(abf16base + knext + qq * 8);
      }
#pragma unroll
      for (int qq = 0; qq < 4; ++qq)
        pbb[qq] = *reinterpret_cast<const short8v*>(bbase + knext + qq * 8);
    }

    // ---- MFMA on the staged tile (hides the prefetch latency)
#pragma unroll
    for (int kk = 0; kk < 2; ++kk) {
      short8v af[4], bf[4];
#pragma unroll
      for (int mi = 0; mi < 4; ++mi)
        af[mi] = *reinterpret_cast<short8v*>(&Asl[wr * 64 + mi * 16 + li][kk * 32 + lg * 8]);
#pragma unroll
      for (int nj = 0; nj < 4; ++nj)
        bf[nj] = *reinterpret_cast<short8v*>(&Bsl[wc * 64 + nj * 16 + li][kk * 32 + lg * 8]);
#pragma unroll
      for (int mi = 0; mi < 4; ++mi)
#pragma unroll
        for (int nj = 0; nj < 4; ++nj) acc[mi][nj] = MFMA16(af[mi], bf[nj], acc[mi][nj]);
    }

    // ---- publish next tile
    if (kt < 7) {
      __syncthreads();
      if (AF32) {
#pragma unroll
        for (int qq = 0; qq < 4; ++qq) {
          const float4 f0 = paf[2 * qq], f1 = paf[2 * qq + 1];
          short8v o;
          o[0] = (short)f2bf(f0.x); o[1] = (short)f2bf(f0.y);
          o[2] = (short)f2bf(f0.z); o[3] = (short)f2bf(f0.w);
          o[4] = (short)f2bf(f1.x); o[5] = (short)f2bf(f1.y);
          o[6] = (short)f2bf(f1.z); o[7] = (short)f2bf(f1.w);
          *reinterpret_cast<short8v*>(&Asl[sr][sh + qq * 8]) = o;
        }
      } else {
#pragma unroll
        for (int qq = 0; qq < 4; ++qq)
          *reinterpret_cast<short8v*>(&Asl[sr][sh + qq * 8]) = pab[qq];
      }
#pragma unroll
      for (int qq = 0; qq < 4; ++qq)
        *reinterpret_cast<short8v*>(&Bsl[sr][sh + qq * 8]) = pbb[qq];
      __syncthreads();
    }
  }

#pragma unroll
  for (int nj = 0; nj < 4; ++nj) {
    const int col = colBase + wc * 64 + nj * 16 + li;
    const float bv = bias[col];
#pragma unroll
    for (int mi = 0; mi < 4; ++mi) {
      const int row0 = rowBase + wr * 64 + mi * 16 + lg * 4;
      if (OUTMODE == 2) {
        const int hh = col >> 6, dd = col & 63;
        const int bb = row0 >> 10, jj = row0 & 1023;
        unsigned short* dst =
            reinterpret_cast<unsigned short*>(Cout) +
            ((size_t)((bb * 8 + hh) * 64 + dd)) * SEQ + jj;
        float v0 = (acc[mi][nj][0] + bv) * scale;
        float v1 = (acc[mi][nj][1] + bv) * scale;
        float v2 = (acc[mi][nj][2] + bv) * scale;
        float v3 = (acc[mi][nj][3] + bv) * scale;
        *reinterpret_cast<uint2*>(dst) = make_uint2(pk2(v0, v1), pk2(v2, v3));
      } else {
#pragma unroll
        for (int rr = 0; rr < 4; ++rr) {
          const int row = row0 + rr;
          const float v = (acc[mi][nj][rr] + bv) * scale;
          if (OUTMODE == 1)
            reinterpret_cast<float*>(Cout)[(size_t)row * 512 + col] = v;
          else
            reinterpret_cast<unsigned short*>(Cout)[(size_t)row * 512 + col] = f2bf(v);
        }
      }
    }
  }
}

__global__ __launch_bounds__(256) void gemm_qk(
    const float* __restrict__ q, const float* __restrict__ k,
    const unsigned short* __restrict__ Wqt, const unsigned short* __restrict__ Wkt,
    const float* __restrict__ bq, const float* __restrict__ bk,
    unsigned short* __restrict__ qpb, unsigned short* __restrict__ kpb) {
  const int z = blockIdx.z;
  const void* A = z ? (const void*)k : (const void*)q;
  const unsigned short* Wt = z ? Wkt : Wqt;
  const float* bias = z ? bk : bq;
  const float scale = z ? 1.0f : 0.125f;
  void* C = z ? (void*)kpb : (void*)qpb;
  gemm_body<1, 0>(A, Wt, bias, scale, C);
}

__global__ __launch_bounds__(256) void gemm_vp(
    const unsigned short* __restrict__ kpb, const unsigned short* __restrict__ Wvt,
    const float* __restrict__ bv, unsigned short* __restrict__ vtb) {
  gemm_body<0, 2>(kpb, Wvt, bv, 1.0f, vtb);
}

__global__ __launch_bounds__(256) void gemm_out(
    const unsigned short* __restrict__ attnb, const unsigned short* __restrict__ Wot,
    const float* __restrict__ bo, float* __restrict__ out) {
  gemm_body<0, 1>(attnb, Wot, bo, 1.0f, out);
}

// ---------------------------------------------------------------------------
// Traffic-shared MFMA flash attention (R11 version, 56 us verified):
// 512 thr = 8 waves x 16 q-rows; single-buffered K/V (36.9 KB LDS);
// launch_bounds(512,4) -> natural ~56 VGPR, no spills.
// ---------------------------------------------------------------------------
__global__ __launch_bounds__(512, 4) void attn_mfma(
    const unsigned short* __restrict__ qp, const unsigned short* __restrict__ kp,
    const unsigned short* __restrict__ vt, const float* __restrict__ pos,
    const int* __restrict__ qmask, const int* __restrict__ kmask,
    unsigned short* __restrict__ outb) {
  const int bx = blockIdx.x;
  const int qc = bx >> 6, h = (bx >> 3) & 7, b = bx & 7;
  const int t = threadIdx.x, w = t >> 6, lane = t & 63, li = lane & 15, lg = lane >> 4;
  const int qrow = qc * 128 + w * 16;

  __shared__ unsigned short Kl[64 * 72];     // [key][dim], padded
  __shared__ unsigned short Vl[64 * 72];     // [dim][key] (V^T), padded
  __shared__ unsigned short Pl[8][16 * 72];  // per-wave P [query][key]

  const size_t qg = (size_t)(b * SEQ + qrow + li) * DMODEL + h * DH;
  const short8v qf0 = *reinterpret_cast<const short8v*>(qp + qg + lg * 8);
  const short8v qf1 = *reinterpret_cast<const short8v*>(qp + qg + 32 + lg * 8);
  const int qmv = qmask[b * SEQ + qrow + li];

  f32x4 zero4 = {0.f, 0.f, 0.f, 0.f};
  f32x4 acc_o[4];
#pragma unroll
  for (int n = 0; n < 4; ++n) acc_o[n] = zero4;
  float m = -3e38f, l = 0.f;

  const int srow = t >> 3, schk = (t & 7) * 8;
  const unsigned short* kgp = kp + (size_t)(b * SEQ + srow) * DMODEL + h * DH + schk;
  const unsigned short* vgp = vt + ((size_t)((b * 8 + h) * 64) + srow) * SEQ + schk;
  const int sldst = srow * 72 + schk;

  const float* posb = pos + (size_t)(b * SEQ + qrow + li) * SEQ;
  const int* kmb = kmask + b * SEQ;

  {
    short8v kr = *reinterpret_cast<const short8v*>(kgp);
    short8v vr = *reinterpret_cast<const short8v*>(vgp);
    *reinterpret_cast<short8v*>(&Kl[sldst]) = kr;
    *reinterpret_cast<short8v*>(&Vl[sldst]) = vr;
  }
  __syncthreads();

  for (int kt = 0; kt < 16; ++kt) {
    const int kbase = kt * 64;

    // issue next-tile staging loads early (written to LDS at iter end)
    short8v kr, vr;
    if (kt < 15) {
      kr = *reinterpret_cast<const short8v*>(kgp + (size_t)(kbase + 64) * DMODEL);
      vr = *reinterpret_cast<const short8v*>(vgp + kbase + 64);
    }

    f32x4 pvn[4];
    i32x4 kmn[4];
#pragma unroll
    for (int n = 0; n < 4; ++n) {
      pvn[n] = *reinterpret_cast<const f32x4*>(posb + kbase + n * 16 + lg * 4);
      kmn[n] = *reinterpret_cast<const i32x4*>(kmb + kbase + n * 16 + lg * 4);
    }

    // ---- swapped QK^T: x4[n][r] = S[key kbase+n*16+lg*4+r][query qrow+li]
    f32x4 x4[4];
    __builtin_amdgcn_s_setprio(1);
#pragma unroll
    for (int n = 0; n < 4; ++n) {
      short8v kfa = *reinterpret_cast<short8v*>(&Kl[(n * 16 + li) * 72 + lg * 8]);
      short8v kfb = *reinterpret_cast<short8v*>(&Kl[(n * 16 + li) * 72 + 32 + lg * 8]);
      x4[n] = MFMA16(kfa, qf0, zero4);
      x4[n] = MFMA16(kfb, qf1, x4[n]);
    }
    __builtin_amdgcn_s_setprio(0);

    // ---- scores + mask + online softmax (query per li lane)
    float x[4][4];
    float tm = -3e38f;
#pragma unroll
    for (int n = 0; n < 4; ++n)
#pragma unroll
      for (int r = 0; r < 4; ++r) {
        float xx = x4[n][r] + pvn[n][r];
        if ((qmv != 0) != (kmn[n][r] != 0)) xx = -1e30f;
        x[n][r] = xx;
        tm = fmaxf(tm, xx);
      }
    tm = fmaxf(tm, __shfl_xor(tm, 16));
    tm = fmaxf(tm, __shfl_xor(tm, 32));
    const float mn = fmaxf(m, tm);
    const float rs = __expf(m - mn);
    m = mn;
    float psum = 0.f;
#pragma unroll
    for (int n = 0; n < 4; ++n)
#pragma unroll
      for (int r = 0; r < 4; ++r) {
        const float p = __expf(x[n][r] - m);
        x[n][r] = p;
        psum += p;
      }
    psum += __shfl_xor(psum, 16);
    psum += __shfl_xor(psum, 32);
    l = l * rs + psum;
    float rsb[4];
#pragma unroll
    for (int r = 0; r < 4; ++r) rsb[r] = __shfl(rs, lg * 4 + r, 16);
#pragma unroll
    for (int n = 0; n < 4; ++n)
#pragma unroll
      for (int r = 0; r < 4; ++r) acc_o[n][r] *= rsb[r];

    // ---- P^T -> per-wave LDS (query-row layout), wave-local fence
#pragma unroll
    for (int n = 0; n < 4; ++n) {
      *reinterpret_cast<uint2*>(&Pl[w][li * 72 + n * 16 + lg * 4]) =
          make_uint2(pk2(x[n][0], x[n][1]), pk2(x[n][2], x[n][3]));
    }
    asm volatile("s_waitcnt lgkmcnt(0)" ::: "memory");
    __builtin_amdgcn_sched_barrier(0);
    const short8v pf0 = *reinterpret_cast<short8v*>(&Pl[w][li * 72 + lg * 8]);
    const short8v pf1 = *reinterpret_cast<short8v*>(&Pl[w][li * 72 + 32 + lg * 8]);

    // ---- PV from staged V^T tile
    __builtin_amdgcn_s_setprio(1);
#pragma unroll
    for (int n = 0; n < 4; ++n) {
      short8v vfa = *reinterpret_cast<short8v*>(&Vl[(n * 16 + li) * 72 + lg * 8]);
      short8v vfb = *reinterpret_cast<short8v*>(&Vl[(n * 16 + li) * 72 + 32 + lg * 8]);
      acc_o[n] = MFMA16(pf0, vfa, acc_o[n]);
      acc_o[n] = MFMA16(pf1, vfb, acc_o[n]);
    }
    __builtin_amdgcn_s_setprio(0);

    // ---- single-buffer swap: drain readers, overwrite, publish
    if (kt < 15) {
      __syncthreads();
      *reinterpret_cast<short8v*>(&Kl[sldst]) = kr;
      *reinterpret_cast<short8v*>(&Vl[sldst]) = vr;
      __syncthreads();
    }
  }

  const float linv = 1.f / l;
  float lb[4];
#pragma unroll
  for (int r = 0; r < 4; ++r) lb[r] = __shfl(linv, lg * 4 + r, 16);
  unsigned short* ob = outb + (size_t)(b * SEQ + qrow) * DMODEL + h * DH;
#pragma unroll
  for (int n = 0; n < 4; ++n)
#pragma unroll
    for (int r = 0; r < 4; ++r)
      ob[(size_t)(lg * 4 + r) * DMODEL + n * 16 + li] = f2bf(acc_o[n][r] * lb[r]);
}

// ---------------------------------------------------------------------------
extern "C" void kernel_launch(void* const* d_in, const int* in_sizes, int n_in,
                              void* d_out, int out_size, void* d_ws, size_t ws_size,
                              hipStream_t stream) {
  const float* q   = (const float*)d_in[0];
  const float* k   = (const float*)d_in[1];
  const int*   qm  = (const int*)d_in[2];
  const int*   km  = (const int*)d_in[3];
  const float* pos = (const float*)d_in[4];
  const float* Wq  = (const float*)d_in[5];
  const float* bq  = (const float*)d_in[6];
  const float* Wk  = (const float*)d_in[7];
  const float* bk  = (const float*)d_in[8];
  const float* Wv  = (const float*)d_in[9];
  const float* bv  = (const float*)d_in[10];
  const float* Wo  = (const float*)d_in[11];
  const float* bo  = (const float*)d_in[12];
  float* out = (float*)d_out;

  char* ws = (char*)d_ws;
  const size_t MB8 = (size_t)TOK * DMODEL * 2;  // 8 MB per bf16 [8192][512]
  unsigned short* qpb   = (unsigned short*)(ws);
  unsigned short* kpb   = (unsigned short*)(ws + 1 * MB8);
  unsigned short* attnb = (unsigned short*)(ws + 2 * MB8);
  unsigned short* vtb   = (unsigned short*)(ws + 3 * MB8);
  unsigned short* Wqt   = (unsigned short*)(ws + 4 * MB8);
  unsigned short* Wkt   = Wqt + (size_t)512 * 512;
  unsigned short* Wvt   = Wkt + (size_t)512 * 512;
  unsigned short* Wot   = Wvt + (size_t)512 * 512;

  hipLaunchKernelGGL(wtr4_kernel, dim3(8, 8, 4), dim3(256), 0, stream,
                     Wq, Wk, Wv, Wo, Wqt, Wkt, Wvt, Wot);

  const dim3 ggrid(DMODEL / 128, TOK / 128);  // (4, 64)
  hipLaunchKernelGGL(gemm_qk, dim3(4, 64, 2), dim3(256), 0, stream,
                     q, k, Wqt, Wkt, bq, bk, qpb, kpb);
  hipLaunchKernelGGL(gemm_vp, ggrid, dim3(256), 0, stream, kpb, Wvt, bv, vtb);

  hipLaunchKernelGGL(attn_mfma, dim3(512), dim3(512), 0, stream,
                     qpb, kpb, vtb, pos, qm, km, attnb);

  hipLaunchKernelGGL(gemm_out, ggrid, dim3(256), 0, stream, attnb, Wot, bo, out);
}